// Round 8
// baseline (872.463 us; speedup 1.0000x reference)
//
#include <hip/hip_runtime.h>
#include <math.h>

#define NBV 65536
#define EV  1048576
#define BV  128
#define K1V 410
#define K2V 205
#define K3V 103
#define NL2 (BV*K2V)     // 26240 live nodes after pool2 (GEMM3/gat domain)
#define NEG_BIG (-1.0e38f)

__device__ __forceinline__ float lrelu(float x){ return x > 0.f ? x : 0.2f*x; }

// ---------------- init: sentinel + nmask + dcnt + fill (1 launch) ----------------
__global__ void k_init1(float* nmask, int* dcnt, int* fill, float* out, float sval){
  int i = blockIdx.x*blockDim.x + threadIdx.x;
  if (i < 128) out[i] = sval;
  if (i < NBV) nmask[i] = 1.f;
  if (i < NBV+1){ dcnt[i] = 0; fill[i] = 0; }
}

// ---------------- CSR build (int atomics only) ----------------
__global__ void k_hist(const int* dst, int* dcnt){
  int e = blockIdx.x*blockDim.x + threadIdx.x;
  if (e < EV) atomicAdd(&dcnt[dst[e]], 1);
}

__global__ void k_scan1(const int* dcnt, int* rp, int* bsum){
  __shared__ int sc[256];
  int t = threadIdx.x, i = blockIdx.x*256 + t;
  int v = dcnt[i];
  sc[t] = v; __syncthreads();
  for (int o = 1; o < 256; o <<= 1){
    int x = (t >= o) ? sc[t-o] : 0;
    __syncthreads();
    sc[t] += x;
    __syncthreads();
  }
  rp[i] = sc[t];
  if (t == 255) bsum[blockIdx.x] = sc[t];
}

__global__ void k_scan2(int* bsum){
  __shared__ int sc[256];
  int t = threadIdx.x;
  int v = bsum[t];
  sc[t] = v; __syncthreads();
  for (int o = 1; o < 256; o <<= 1){
    int x = (t >= o) ? sc[t-o] : 0;
    __syncthreads();
    sc[t] += x;
    __syncthreads();
  }
  bsum[t] = sc[t] - v;
}

__global__ void k_scan3(int* rp, const int* dcnt, const int* bsum){
  int t = threadIdx.x, i = blockIdx.x*256 + t;
  rp[i] = rp[i] - dcnt[i] + bsum[blockIdx.x];
  if (i == 0) rp[NBV] = EV;
}

__global__ void k_scatter(const int* src, const int* dst, const int* rp, int* fill,
                          int* csr_src, int* csr_eid){
  int e = blockIdx.x*blockDim.x + threadIdx.x;
  if (e < EV){
    int d = dst[e];
    int pos = atomicAdd(&fill[d], 1);
    int slot = rp[d] + pos;
    csr_src[slot] = src[e];
    csr_eid[slot] = e;
  }
}

// ---------------- small precomputes (merged: ve + invnorm, 1 launch) ----------------
__global__ void k_ve_inv(const float* g_we, const float* g_ae, const float* p1w, float* sml){
  __shared__ float sc[128];
  int t = threadIdx.x;
  if (t < 28){
    int ed = t >> 2, h = t & 3;
    float a = 0.f;
    for (int c = 0; c < 32; c++) a += g_we[ed*128 + h*32 + c] * g_ae[h*32 + c];
    sml[20 + t] = a;
  }
  float v = p1w[t];
  sc[t] = v*v; __syncthreads();
  for (int o = 64; o > 0; o >>= 1){ if (t < o) sc[t] += sc[t+o]; __syncthreads(); }
  if (t == 0) sml[0] = 1.f / sqrtf(sc[0]);
}

__global__ void k_ale(const float* ea, const float* ve, float* ALE){
  int e = blockIdx.x*blockDim.x + threadIdx.x;
  if (e < EV){
    float a0=0.f,a1=0.f,a2=0.f,a3=0.f;
    for (int ed = 0; ed < 7; ed++){
      float x = ea[e*7 + ed];
      a0 += x*ve[ed*4+0]; a1 += x*ve[ed*4+1]; a2 += x*ve[ed*4+2]; a3 += x*ve[ed*4+3];
    }
    float4 o; o.x=a0; o.y=a1; o.z=a2; o.w=a3;
    *(float4*)&ALE[(size_t)e*4] = o;
  }
}

// ---------------- dual GEMM f32, W-resident, fused SAGE-gather A pipeline ---------
// PROVEN core (R5/R7): 71.4 us/dispatch, 64 VGPR, zero scratch, LDS 72.5KB
// (2 blk/CU; VGPR budget there is 128 so headroom exists).
// REFUTED (R6): full-tile LDS (132KB) -> 1 blk/CU exposes ds_read latency.
// REFUTED (r13-r15): K-chunk W-streaming + dbuf spills at ANY VGPR budget.
// __launch_bounds__ arg2 on this toolchain = CUDA-style min-BLOCKS-per-CU.
// NEW (r18): agg_mode gathers+means the SAGE neighbor rows directly in the
// A-prefetch slot (hidden under the 1024-cyc FMA burst per chunk), replacing
// the separate k_sage_agg kernel + AGG round-trip. Neighbor sums walk the CSR
// list in the same sequential s-order as k_sage_agg did (its 4-unroll also
// added in order), cnt/inv identical -> bitwise identical A tiles.
// sc_mode: 0=none, 1=score1 (tanh(dot*inv)), 2=qr dual-dot, 3=GAT heads.
__global__ void __launch_bounds__(512) k_gemm(const float* A1, const float* A2,
    const float* W1, const float* W2, const float* bias,
    float* OUT, int has2, int relu, int hasb,
    const int* ridx, int sc_mode,
    const float* sw1, const float* sw2, const float* sinv,
    float* so1, float* so2,
    int agg_mode, const float* nmask, const int* rp, const int* csr_src){
  __shared__ float ws[128][128];
  __shared__ float as[16][136];
  int t = threadIdx.x;
  int n0 = blockIdx.x * 128;
  int rowg = t >> 5;
  int colg = t & 31;
  int rb = rowg * 8;
  int jb = colg * 4;
  int an = t >> 2;              // A-stage row 0..127
  int ak = (t & 3) << 2;        // A-stage k offset {0,4,8,12}
  int arow = ridx ? ridx[n0 + an] : (n0 + an);
  float acc[8][4];
  for (int r = 0; r < 8; r++)
    for (int j = 0; j < 4; j++) acc[r][j] = 0.f;
  int nmat = has2 ? 2 : 1;
  for (int m = 0; m < nmat; m++){
    const float* A = (m == 0) ? A1 : A2;
    const float* W = (m == 0) ? W1 : W2;
    bool agg = (m == 0) && (agg_mode != 0);
    __syncthreads();   // prior readers of ws/as done (no-op cost at m==0)
    for (int ii = 0; ii < 8; ii++){
      int idx4 = t + 512*ii;
      int kk = idx4 >> 5;
      int jj = (idx4 & 31) << 2;
      *(float4*)&ws[kk][jj] = *(const float4*)&W[kk*128 + jj];
    }
    float4 rA;
    float ax=0.f, ay=0.f, az=0.f, aw=0.f, invn = 1.f;
    int nr0 = 0, nr1 = 0;
    bool rowlive = true;
    if (agg){
      nr0 = rp[arow]; nr1 = rp[arow+1];
      if (agg_mode == 2 && !(nmask[arow] > 0.f)) rowlive = false;
      float cnt = 0.f;
      if (rowlive){
        for (int s2 = nr0; s2 < nr1; s2++){
          int sn = csr_src[s2];
          float nm = (agg_mode == 2) ? nmask[sn] : 1.f;
          if (nm > 0.f){
            float4 v = *(const float4*)&A[((size_t)sn << 7) + ak];
            ax += v.x; ay += v.y; az += v.z; aw += v.w; cnt += 1.f;
          }
        }
      }
      invn = 1.f / fmaxf(cnt, 1.f);
    } else {
      rA = *(const float4*)&A[((size_t)arow << 7) + ak];   // chunk 0
    }
    for (int c = 0; c < 8; c++){
      if (c > 0) __syncthreads();        // prior compute done reading as
      if (agg){
        as[ak+0][an] = ax*invn;
        as[ak+1][an] = ay*invn;
        as[ak+2][an] = az*invn;
        as[ak+3][an] = aw*invn;
      } else {
        as[ak+0][an] = rA.x;
        as[ak+1][an] = rA.y;
        as[ak+2][an] = rA.z;
        as[ak+3][an] = rA.w;
      }
      __syncthreads();                   // as (and ws on c==0) visible
      if (c+1 < 8){                      // prefetch/gather next chunk (hidden under FMAs)
        if (agg){
          ax = ay = az = aw = 0.f;
          if (rowlive){
            int kb2 = (c+1)*16 + ak;
            for (int s2 = nr0; s2 < nr1; s2++){
              int sn = csr_src[s2];
              float nm = (agg_mode == 2) ? nmask[sn] : 1.f;
              if (nm > 0.f){
                float4 v = *(const float4*)&A[((size_t)sn << 7) + kb2];
                ax += v.x; ay += v.y; az += v.z; aw += v.w;
              }
            }
          }
        } else {
          rA = *(const float4*)&A[((size_t)arow << 7) + (c+1)*16 + ak];
        }
      }
      int kb = c*16;
      for (int kk = 0; kk < 16; kk++){
        float4 wv = *(const float4*)&ws[kb+kk][jb];
        float4 aL = *(const float4*)&as[kk][rb];
        float4 aH = *(const float4*)&as[kk][rb+4];
        float a0=aL.x,a1=aL.y,a2=aL.z,a3=aL.w,a4=aH.x,a5=aH.y,a6=aH.z,a7=aH.w;
        acc[0][0]+=a0*wv.x; acc[0][1]+=a0*wv.y; acc[0][2]+=a0*wv.z; acc[0][3]+=a0*wv.w;
        acc[1][0]+=a1*wv.x; acc[1][1]+=a1*wv.y; acc[1][2]+=a1*wv.z; acc[1][3]+=a1*wv.w;
        acc[2][0]+=a2*wv.x; acc[2][1]+=a2*wv.y; acc[2][2]+=a2*wv.z; acc[2][3]+=a2*wv.w;
        acc[3][0]+=a3*wv.x; acc[3][1]+=a3*wv.y; acc[3][2]+=a3*wv.z; acc[3][3]+=a3*wv.w;
        acc[4][0]+=a4*wv.x; acc[4][1]+=a4*wv.y; acc[4][2]+=a4*wv.z; acc[4][3]+=a4*wv.w;
        acc[5][0]+=a5*wv.x; acc[5][1]+=a5*wv.y; acc[5][2]+=a5*wv.z; acc[5][3]+=a5*wv.w;
        acc[6][0]+=a6*wv.x; acc[6][1]+=a6*wv.y; acc[6][2]+=a6*wv.z; acc[6][3]+=a6*wv.w;
        acc[7][0]+=a7*wv.x; acc[7][1]+=a7*wv.y; acc[7][2]+=a7*wv.z; acc[7][3]+=a7*wv.w;
      }
    }
  }
  float bj0=0.f,bj1=0.f,bj2=0.f,bj3=0.f;
  if (hasb){
    bj0 = bias[jb+0]; bj1 = bias[jb+1]; bj2 = bias[jb+2]; bj3 = bias[jb+3];
  }
  int orow[8];
  for (int r = 0; r < 8; r++) orow[r] = ridx ? ridx[n0+rb+r] : (n0+rb+r);
  float w1x=0.f,w1y=0.f,w1z=0.f,w1w=0.f, w2x=0.f,w2y=0.f,w2z=0.f,w2w=0.f;
  if (sc_mode){
    float4 t1 = *(const float4*)&sw1[jb];
    w1x=t1.x; w1y=t1.y; w1z=t1.z; w1w=t1.w;
    if (sc_mode >= 2){
      float4 t2 = *(const float4*)&sw2[jb];
      w2x=t2.x; w2y=t2.y; w2z=t2.z; w2w=t2.w;
    }
  }
  float pd1[8], pd2[8];
  for (int r = 0; r < 8; r++){
    float4 o;
    o.x = acc[r][0]+bj0; o.y = acc[r][1]+bj1; o.z = acc[r][2]+bj2; o.w = acc[r][3]+bj3;
    if (relu){
      o.x = fmaxf(o.x,0.f); o.y = fmaxf(o.y,0.f); o.z = fmaxf(o.z,0.f); o.w = fmaxf(o.w,0.f);
    }
    if (sc_mode){
      pd1[r] = o.x*w1x + o.y*w1y + o.z*w1z + o.w*w1w;
      if (sc_mode >= 2) pd2[r] = o.x*w2x + o.y*w2y + o.z*w2z + o.w*w2w;
    }
    *(float4*)&OUT[((size_t)orow[r] << 7) + jb] = o;
  }
  if (sc_mode == 1){
    float inv = sinv[0];
    for (int r = 0; r < 8; r++){
      float a = pd1[r];
      for (int o = 16; o > 0; o >>= 1) a += __shfl_down(a, o, 32);
      if (colg == 0) so1[orow[r]] = tanhf(a * inv);
    }
  } else if (sc_mode == 2){
    for (int r = 0; r < 8; r++){
      float a = pd1[r];
      float b = pd2[r];
      for (int o = 16; o > 0; o >>= 1){
        a += __shfl_down(a, o, 32);
        b += __shfl_down(b, o, 32);
      }
      if (colg == 0){ so1[orow[r]] = a; so2[orow[r]] = b; }
    }
  } else if (sc_mode == 3){
    // fused k_heads: serial accumulate lanes h*8..h*8+7 in c4 order (bit-exact)
    int base = colg & ~7;
    for (int r = 0; r < 8; r++){
      float s1 = 0.f, s2 = 0.f;
      for (int c4 = 0; c4 < 8; c4++){
        s1 += __shfl(pd1[r], base + c4, 32);
        s2 += __shfl(pd2[r], base + c4, 32);
      }
      if ((colg & 7) == 0){
        int h = colg >> 3;
        so1[orow[r]*4 + h] = s1;
        so2[orow[r]*4 + h] = s2;
      }
    }
  }
}

__global__ void k_gconv(const float* q, const float* r, const float* nmask,
    const int* rp, const int* csr_src, const float* brel, float* s){
  int i = blockIdx.x*blockDim.x + threadIdx.x;
  if (i >= NBV) return;
  float acc = 0.f;
  if (nmask[i] > 0.f){
    int r0 = rp[i], r1 = rp[i+1];
    int t2 = r0;
    for (; t2 + 4 <= r1; t2 += 4){
      int sn0 = csr_src[t2+0], sn1 = csr_src[t2+1], sn2 = csr_src[t2+2], sn3 = csr_src[t2+3];
      float nm0 = nmask[sn0], nm1 = nmask[sn1], nm2 = nmask[sn2], nm3 = nmask[sn3];
      if (nm0 > 0.f) acc += q[sn0];
      if (nm1 > 0.f) acc += q[sn1];
      if (nm2 > 0.f) acc += q[sn2];
      if (nm3 > 0.f) acc += q[sn3];
    }
    for (; t2 < r1; t2++){
      int sn = csr_src[t2];
      if (nmask[sn] > 0.f) acc += q[sn];
    }
  }
  s[i] = tanhf(acc + brel[0] + r[i]);
}

// ---------------- fused top-k pool + scale + gap (1 launch instead of 3) --------
__global__ void __launch_bounds__(512) k_poolscale(const float* s, float* nmask,
    float* X, float* gap, int K, int* cidx, float invK){
  __shared__ float sc[512];     // scores for rank; reused as live-flags after
  __shared__ float lsel[512];
  __shared__ float prt[8][128];
  int b = blockIdx.x, t = threadIdx.x;
  int i = b*512 + t;
  float nm = nmask[i];
  float sv = s[i];
  float ms = (nm > 0.f) ? sv : NEG_BIG;
  sc[t] = ms;
  __syncthreads();
  int rank = 0;
  for (int j = 0; j < 512; j++){
    float o = sc[j];
    rank += ((o > ms) || (o == ms && j < t)) ? 1 : 0;
  }
  bool selb = rank < K;
  nmask[i] = selb ? 1.f : 0.f;
  if (cidx && selb) cidx[b*K + rank] = i;
  __syncthreads();              // all rank reads of sc done
  sc[t] = selb ? 1.f : 0.f;     // live flag
  lsel[t] = selb ? sv : 0.f;
  __syncthreads();
  int c = t & 127, g = t >> 7;  // 128 cols x 4 groups; group handles q=2g,2g+1
  for (int qq = 0; qq < 2; qq++){
    int q = g*2 + qq;
    float acc = 0.f;
    for (int n = q*64; n < q*64 + 64; n++){
      if (sc[n] > 0.f){
        size_t idx = (((size_t)(b*512 + n)) << 7) + c;
        float v = X[idx] * lsel[n];
        X[idx] = v;
        acc += v;
      }
    }
    prt[q][c] = acc;
  }
  __syncthreads();
  if (t < 128){
    float ss = 0.f;
    for (int q = 0; q < 8; q++) ss += prt[q][t];
    gap[b*128 + t] = ss * invK;
  }
}

// edge-attr masked mean: per-block partials (no atomics)
__global__ void __launch_bounds__(256) k_ea_part(const float* ea, const int* srcA, const int* dstA,
    const float* nmask, float* part){
  float p[8] = {0.f,0.f,0.f,0.f,0.f,0.f,0.f,0.f};
  for (int e = blockIdx.x*256 + threadIdx.x; e < EV; e += 256*256){
    if (nmask[srcA[e]] > 0.f && nmask[dstA[e]] > 0.f){
      for (int d = 0; d < 7; d++) p[d] += ea[e*7 + d];
      p[7] += 1.f;
    }
  }
  __shared__ float red[256];
  for (int comp = 0; comp < 8; comp++){
    red[threadIdx.x] = p[comp]; __syncthreads();
    for (int o = 128; o > 0; o >>= 1){ if (threadIdx.x < o) red[threadIdx.x] += red[threadIdx.x + o]; __syncthreads(); }
    if (threadIdx.x == 0) part[blockIdx.x*8 + comp] = red[0];
    __syncthreads();
  }
}

// merged ea_final + alse
__global__ void k_ea_fin(const float* part, const float* ve, float* alse){
  __shared__ float es[8];
  int h = threadIdx.x;
  if (h < 8){
    float s = 0.f;
    for (int b = 0; b < 256; b++) s += part[b*8 + h];
    es[h] = s;
  }
  __syncthreads();
  if (h == 0){
    float cnt = fmaxf(es[7], 1.f);
    for (int hh = 0; hh < 4; hh++){
      float s = 0.f;
      for (int ed = 0; ed < 7; ed++) s += (es[ed]/cnt) * ve[ed*4 + hh];
      alse[hh] = s;
    }
  }
}

// GAT: 32 threads/node, compacted to live2 nodes, mask-gated gathers + in-order
// online softmax. Epilogue fuses k_qr (p3) bit-exactly (same dot + shfl tree).
__global__ void __launch_bounds__(256) k_gat(const float* xs, const float* alS, const float* alD,
    const float* ALE, const float* nmask, const int* rp, const int* csr_src,
    const int* csr_eid, const float* alse, const float* g_b,
    const float* wrel, const float* wroot, const int* nidx, int kper,
    float* qv, float* rv, float* OUT){
  int g = blockIdx.x & 127;
  int blk = blockIdx.x >> 7;
  int r = blk*8 + (threadIdx.x >> 5);
  int i;
  if (nidx){ if (r >= kper) return; i = nidx[g*kper + r]; }
  else i = g*512 + r;
  int lane = threadIdx.x & 31;
  int h = lane >> 3;
  int ch = h*8 + (lane & 7);   // == lane
  float nmi = nmask[i];
  const float4* xs4 = (const float4*)xs;
  float m = 0.f, den = 0.f;
  float4 acc; acc.x=0.f; acc.y=0.f; acc.z=0.f; acc.w=0.f;
  if (nmi > 0.f){
    float ald_i = alD[i*4 + h];
    m = lrelu(alS[i*4 + h] + ald_i + alse[h]);   // aself
    den = 1.f;
    acc = xs4[(size_t)i*32 + ch];
    int r0 = rp[i], r1 = rp[i+1];
    int s = r0;
    for (; s + 4 <= r1; s += 4){
      int sn0 = csr_src[s+0], sn1 = csr_src[s+1], sn2 = csr_src[s+2], sn3 = csr_src[s+3];
      float nm0 = nmask[sn0], nm1 = nmask[sn1], nm2 = nmask[sn2], nm3 = nmask[sn3];
      if (nm0 > 0.f){
        float a = lrelu(alS[sn0*4 + h] + ald_i + ALE[(size_t)csr_eid[s+0]*4 + h]);
        float4 v = xs4[(size_t)sn0*32 + ch];
        float mn = fmaxf(m, a); float pm = expf(m - mn); float pa = expf(a - mn);
        den = den*pm + pa;
        acc.x = acc.x*pm + pa*v.x; acc.y = acc.y*pm + pa*v.y;
        acc.z = acc.z*pm + pa*v.z; acc.w = acc.w*pm + pa*v.w;
        m = mn;
      }
      if (nm1 > 0.f){
        float a = lrelu(alS[sn1*4 + h] + ald_i + ALE[(size_t)csr_eid[s+1]*4 + h]);
        float4 v = xs4[(size_t)sn1*32 + ch];
        float mn = fmaxf(m, a); float pm = expf(m - mn); float pa = expf(a - mn);
        den = den*pm + pa;
        acc.x = acc.x*pm + pa*v.x; acc.y = acc.y*pm + pa*v.y;
        acc.z = acc.z*pm + pa*v.z; acc.w = acc.w*pm + pa*v.w;
        m = mn;
      }
      if (nm2 > 0.f){
        float a = lrelu(alS[sn2*4 + h] + ald_i + ALE[(size_t)csr_eid[s+2]*4 + h]);
        float4 v = xs4[(size_t)sn2*32 + ch];
        float mn = fmaxf(m, a); float pm = expf(m - mn); float pa = expf(a - mn);
        den = den*pm + pa;
        acc.x = acc.x*pm + pa*v.x; acc.y = acc.y*pm + pa*v.y;
        acc.z = acc.z*pm + pa*v.z; acc.w = acc.w*pm + pa*v.w;
        m = mn;
      }
      if (nm3 > 0.f){
        float a = lrelu(alS[sn3*4 + h] + ald_i + ALE[(size_t)csr_eid[s+3]*4 + h]);
        float4 v = xs4[(size_t)sn3*32 + ch];
        float mn = fmaxf(m, a); float pm = expf(m - mn); float pa = expf(a - mn);
        den = den*pm + pa;
        acc.x = acc.x*pm + pa*v.x; acc.y = acc.y*pm + pa*v.y;
        acc.z = acc.z*pm + pa*v.z; acc.w = acc.w*pm + pa*v.w;
        m = mn;
      }
    }
    for (; s < r1; s++){
      int sn = csr_src[s];
      if (nmask[sn] > 0.f){
        float a = lrelu(alS[sn*4 + h] + ald_i + ALE[(size_t)csr_eid[s]*4 + h]);
        float4 v = xs4[(size_t)sn*32 + ch];
        float mn = fmaxf(m, a); float pm = expf(m - mn); float pa = expf(a - mn);
        den = den*pm + pa;
        acc.x = acc.x*pm + pa*v.x; acc.y = acc.y*pm + pa*v.y;
        acc.z = acc.z*pm + pa*v.z; acc.w = acc.w*pm + pa*v.w;
        m = mn;
      }
    }
  }
  den = fmaxf(den, 1e-16f);
  float rd = 1.f/den;
  int cb = ch << 2;
  float4 o;
  o.x = fmaxf(acc.x*rd + g_b[cb+0], 0.f);
  o.y = fmaxf(acc.y*rd + g_b[cb+1], 0.f);
  o.z = fmaxf(acc.z*rd + g_b[cb+2], 0.f);
  o.w = fmaxf(acc.w*rd + g_b[cb+3], 0.f);
  *(float4*)&OUT[((size_t)i << 7) + cb] = o;
  // fused k_qr (p3): identical per-lane dot + width-32 tree as standalone k_qr
  float4 wa = *(const float4*)&wrel[cb];
  float4 wb = *(const float4*)&wroot[cb];
  float aq = o.x*wa.x + o.y*wa.y + o.z*wa.z + o.w*wa.w;
  float ar = o.x*wb.x + o.y*wb.y + o.z*wb.z + o.w*wb.w;
  for (int off = 16; off > 0; off >>= 1){
    aq += __shfl_down(aq, off, 32);
    ar += __shfl_down(ar, off, 32);
  }
  if (lane == 0){ qv[i] = aq; rv[i] = ar; }
}

// ---------------- final MLP ----------------
__global__ void __launch_bounds__(128) k_mlp(const float* x1g, const float* x2g, const float* x3g,
    const float* l1w, const float* l1b, const float* l2w, const float* l2b,
    const float* l3w, const float* l3b, float* out){
  __shared__ float hh[128];
  __shared__ float h2[128];
  __shared__ float h3[64];
  int b = blockIdx.x, t = threadIdx.x;
  hh[t] = x1g[b*128 + t] + x2g[b*128 + t] + x3g[b*128 + t];
  __syncthreads();
  float a = l1b[t];
  for (int k = 0; k < 128; k++) a += hh[k] * l1w[k*128 + t];
  h2[t] = fmaxf(a, 0.f);
  __syncthreads();
  if (t < 64){
    float a2 = l2b[t];
    for (int k = 0; k < 128; k++) a2 += h2[k] * l2w[k*64 + t];
    h3[t] = fmaxf(a2, 0.f);
  }
  __syncthreads();
  if (t == 0){
    float z = l3b[0];
    for (int k = 0; k < 64; k++) z += h3[k] * l3w[k];
    out[b] = 1.f/(1.f + expf(-z));
  }
}

// ---------------- launch ----------------
extern "C" void kernel_launch(void* const* d_in, const int* in_sizes, int n_in,
                              void* d_out, int out_size, void* d_ws, size_t ws_size,
                              hipStream_t stream){
  const float* x       = (const float*)d_in[0];
  const int*   ei      = (const int*)d_in[1];
  const float* ea      = (const float*)d_in[2];
  const float* c1_wl   = (const float*)d_in[3];
  const float* c1_bl   = (const float*)d_in[4];
  const float* c1_wr   = (const float*)d_in[5];
  const float* p1_w    = (const float*)d_in[6];
  const float* c2_wl   = (const float*)d_in[7];
  const float* c2_bl   = (const float*)d_in[8];
  const float* c2_wr   = (const float*)d_in[9];
  const float* p2_wrel = (const float*)d_in[10];
  const float* p2_brel = (const float*)d_in[11];
  const float* p2_wroot= (const float*)d_in[12];
  const float* g_w     = (const float*)d_in[13];
  const float* g_as    = (const float*)d_in[14];
  const float* g_ad    = (const float*)d_in[15];
  const float* g_we    = (const float*)d_in[16];
  const float* g_ae    = (const float*)d_in[17];
  const float* g_b     = (const float*)d_in[18];
  const float* p3_wrel = (const float*)d_in[19];
  const float* p3_brel = (const float*)d_in[20];
  const float* p3_wroot= (const float*)d_in[21];
  const float* l1_w    = (const float*)d_in[22];
  const float* l1_b    = (const float*)d_in[23];
  const float* l2_w    = (const float*)d_in[24];
  const float* l2_b    = (const float*)d_in[25];
  const float* l3_w    = (const float*)d_in[26];
  const float* l3_b    = (const float*)d_in[27];
  float* out = (float*)d_out;
  (void)in_sizes; (void)n_in; (void)out_size;

  // Workspace layout (f32, ~137 MB)
  char* w = (char*)d_ws;
  size_t off = 0;
  float* AGG  = (float*)(w + off); off += (size_t)NBV*128*4;   // xs for block 3
  float* F1   = (float*)(w + off); off += (size_t)NBV*128*4;
  float* F2   = (float*)(w + off); off += (size_t)NBV*128*4;
  float* ALE  = (float*)(w + off); off += (size_t)EV*4*4;
  float* sA   = (float*)(w + off); off += (size_t)NBV*4;
  float* qv   = (float*)(w + off); off += (size_t)NBV*4;
  float* rv   = (float*)(w + off); off += (size_t)NBV*4;
  float* nmask= (float*)(w + off); off += (size_t)NBV*4;
  float* alS  = (float*)(w + off); off += (size_t)NBV*4*4;
  float* alD  = (float*)(w + off); off += (size_t)NBV*4*4;
  float* x1g  = (float*)(w + off); off += (size_t)BV*128*4;
  float* x2g  = (float*)(w + off); off += (size_t)BV*128*4;
  float* x3g  = (float*)(w + off); off += (size_t)BV*128*4;
  float* sml  = (float*)(w + off); off += 64*4;      // [0]=invnorm [16..19]=alse [20..47]=ve
  float* eprt = (float*)(w + off); off += 2048*4;
  int* csr_src = (int*)(w + off); off += (size_t)EV*4;
  int* csr_eid = (int*)(w + off); off += (size_t)EV*4;
  int* rp      = (int*)(w + off); off += (size_t)(NBV+64)*4;
  int* dcnt    = (int*)(w + off); off += (size_t)(NBV+64)*4;
  int* fill    = (int*)(w + off); off += (size_t)(NBV+64)*4;
  int* cidx1   = (int*)(w + off); off += (size_t)NBV*4;
  int* cidx2   = (int*)(w + off); off += (size_t)NBV*4;
  int* bsum    = (int*)(w + off); off += 1024;
  size_t needed = off;

  float sentinel = (ws_size >= needed) ? 0.125f : 0.875f;

  const int* srcA = ei;
  const int* dstA = ei + EV;

  // ---- setup (sentinel folded into init1) ----
  k_init1<<<(NBV+256)/256, 256, 0, stream>>>(nmask, dcnt, fill, out, sentinel);
  k_hist<<<EV/256, 256, 0, stream>>>(dstA, dcnt);
  k_scan1<<<256, 256, 0, stream>>>(dcnt, rp, bsum);
  k_scan2<<<1, 256, 0, stream>>>(bsum);
  k_scan3<<<256, 256, 0, stream>>>(rp, dcnt, bsum);
  k_scatter<<<EV/256, 256, 0, stream>>>(srcA, dstA, rp, fill, csr_src, csr_eid);
  k_ve_inv<<<1, 128, 0, stream>>>(g_we, g_ae, p1_w, sml);
  k_ale<<<EV/256, 256, 0, stream>>>(ea, sml+20, ALE);

  // ---- block 1: fused SAGE-gather GEMM -> TopK(410)+scale+gap  (x -> F1) ----
  k_gemm<<<NBV/128, 512, 0, stream>>>(x, x, c1_wl, c1_wr, c1_bl, F1, 1, 1, 1,
                                      (const int*)nullptr, 1, p1_w, (const float*)nullptr, sml, sA, (float*)nullptr,
                                      1, nmask, rp, csr_src);
  k_poolscale<<<BV, 512, 0, stream>>>(sA, nmask, F1, x1g, K1V, cidx1, 1.f/(float)K1V);

  // ---- block 2: fused masked SAGE-gather GEMM -> SAGPool(205)+scale+gap ----
  k_gemm<<<NBV/128, 512, 0, stream>>>(F1, F1, c2_wl, c2_wr, c2_bl, F2, 1, 1, 1,
                                      (const int*)nullptr, 2, p2_wrel, p2_wroot, (const float*)nullptr, qv, rv,
                                      2, nmask, rp, csr_src);
  k_gconv<<<NBV/256, 256, 0, stream>>>(qv, rv, nmask, rp, csr_src, p2_brel, sA);
  k_poolscale<<<BV, 512, 0, stream>>>(sA, nmask, F2, x2g, K2V, cidx2, 1.f/(float)K2V);

  // ---- block 3: GAT (compacted; heads fused in GEMM3) -> SAGPool(103)+scale+gap ----
  k_gemm<<<NL2/128, 512, 0, stream>>>(F2, F2, g_w, g_w, g_b, AGG, 0, 0, 0,
                                      cidx2, 3, g_as, g_ad,
                                      (const float*)nullptr, alS, alD,
                                      0, (const float*)nullptr, (const int*)nullptr, (const int*)nullptr);
  k_ea_part<<<256, 256, 0, stream>>>(ea, srcA, dstA, nmask, eprt);
  k_ea_fin<<<1, 64, 0, stream>>>(eprt, sml+20, sml+16);
  k_gat<<<BV*26, 256, 0, stream>>>(AGG, alS, alD, ALE, nmask, rp, csr_src, csr_eid,
                                   sml+16, g_b, p3_wrel, p3_wroot, cidx2, K2V, qv, rv, F1);
  k_gconv<<<NBV/256, 256, 0, stream>>>(qv, rv, nmask, rp, csr_src, p3_brel, sA);
  k_poolscale<<<BV, 512, 0, stream>>>(sA, nmask, F1, x3g, K3V, (int*)nullptr, 1.f/(float)K3V);

  // ---- readout MLP ----
  k_mlp<<<BV, 128, 0, stream>>>(x1g, x2g, x3g, l1_w, l1_b, l2_w, l2_b, l3_w, l3_b, out);
}

// Round 10
// 685.473 us; speedup vs baseline: 1.2728x; 1.2728x over previous
//
#include <hip/hip_runtime.h>
#include <math.h>

#define NBV 65536
#define EV  1048576
#define BV  128
#define K1V 410
#define K2V 205
#define K3V 103
#define NL1 (BV*K1V)     // 52480 live nodes after pool1 (GEMM2/gconv2 domain)
#define NL2 (BV*K2V)     // 26240 live nodes after pool2 (GEMM3/gat/gconv3 domain)
#define NEG_BIG (-1.0e38f)

__device__ __forceinline__ float lrelu(float x){ return x > 0.f ? x : 0.2f*x; }

// ---------------- init: sentinel + nmask + dcnt + fill (1 launch) ----------------
__global__ void k_init1(float* nmask, int* dcnt, int* fill, float* out, float sval){
  int i = blockIdx.x*blockDim.x + threadIdx.x;
  if (i < 128) out[i] = sval;
  if (i < NBV) nmask[i] = 1.f;
  if (i < NBV+1){ dcnt[i] = 0; fill[i] = 0; }
}

// ---------------- CSR build (int atomics only) ----------------
__global__ void k_hist(const int* dst, int* dcnt){
  int e = blockIdx.x*blockDim.x + threadIdx.x;
  if (e < EV) atomicAdd(&dcnt[dst[e]], 1);
}

__global__ void k_scan1(const int* dcnt, int* rp, int* bsum){
  __shared__ int sc[256];
  int t = threadIdx.x, i = blockIdx.x*256 + t;
  int v = dcnt[i];
  sc[t] = v; __syncthreads();
  for (int o = 1; o < 256; o <<= 1){
    int x = (t >= o) ? sc[t-o] : 0;
    __syncthreads();
    sc[t] += x;
    __syncthreads();
  }
  rp[i] = sc[t];
  if (t == 255) bsum[blockIdx.x] = sc[t];
}

__global__ void k_scan2(int* bsum){
  __shared__ int sc[256];
  int t = threadIdx.x;
  int v = bsum[t];
  sc[t] = v; __syncthreads();
  for (int o = 1; o < 256; o <<= 1){
    int x = (t >= o) ? sc[t-o] : 0;
    __syncthreads();
    sc[t] += x;
    __syncthreads();
  }
  bsum[t] = sc[t] - v;
}

__global__ void k_scan3(int* rp, const int* dcnt, const int* bsum){
  int t = threadIdx.x, i = blockIdx.x*256 + t;
  rp[i] = rp[i] - dcnt[i] + bsum[blockIdx.x];
  if (i == 0) rp[NBV] = EV;
}

__global__ void k_scatter(const int* src, const int* dst, const int* rp, int* fill,
                          int* csr_src, int* csr_eid){
  int e = blockIdx.x*blockDim.x + threadIdx.x;
  if (e < EV){
    int d = dst[e];
    int pos = atomicAdd(&fill[d], 1);
    int slot = rp[d] + pos;
    csr_src[slot] = src[e];
    csr_eid[slot] = e;
  }
}

// ---------------- small precomputes (merged: ve + invnorm, 1 launch) ----------------
__global__ void k_ve_inv(const float* g_we, const float* g_ae, const float* p1w, float* sml){
  __shared__ float sc[128];
  int t = threadIdx.x;
  if (t < 28){
    int ed = t >> 2, h = t & 3;
    float a = 0.f;
    for (int c = 0; c < 32; c++) a += g_we[ed*128 + h*32 + c] * g_ae[h*32 + c];
    sml[20 + t] = a;
  }
  float v = p1w[t];
  sc[t] = v*v; __syncthreads();
  for (int o = 64; o > 0; o >>= 1){ if (t < o) sc[t] += sc[t+o]; __syncthreads(); }
  if (t == 0) sml[0] = 1.f / sqrtf(sc[0]);
}

__global__ void k_ale(const float* ea, const float* ve, float* ALE){
  int e = blockIdx.x*blockDim.x + threadIdx.x;
  if (e < EV){
    float a0=0.f,a1=0.f,a2=0.f,a3=0.f;
    for (int ed = 0; ed < 7; ed++){
      float x = ea[e*7 + ed];
      a0 += x*ve[ed*4+0]; a1 += x*ve[ed*4+1]; a2 += x*ve[ed*4+2]; a3 += x*ve[ed*4+3];
    }
    float4 o; o.x=a0; o.y=a1; o.z=a2; o.w=a3;
    *(float4*)&ALE[(size_t)e*4] = o;
  }
}

// ---------------- SAGE mean aggregation (XCD-swizzled; optional compaction) ----------------
// REFUTED (r18/R8): fusing this gather into the GEMM A-prefetch slot costs 5x
// FETCH (16B-of-random-row reads waste cache lines; neighbor list re-walked 8x)
// and serializes the accumulate chain -> 231us. Keep the standalone kernel:
// 32 lanes/node read each 512B neighbor row once, fully coalesced.
__global__ void __launch_bounds__(256) k_sage_agg(const float* X, const float* nmask,
    const int* rp, const int* csr_src, float* AGG, int masked,
    const int* nidx, int kper){
  int g = blockIdx.x & 127;
  int blk = blockIdx.x >> 7;
  int r = blk*8 + (threadIdx.x >> 5);
  int i;
  if (nidx){ if (r >= kper) return; i = nidx[g*kper + r]; }
  else i = g*512 + r;
  int c4 = threadIdx.x & 31;
  float ax=0.f,ay=0.f,az=0.f,aw=0.f,cnt=0.f;
  if (!masked || nmask[i] > 0.f){
    int r0 = rp[i], r1 = rp[i+1];
    int s = r0;
    for (; s + 4 <= r1; s += 4){
      int sn0 = csr_src[s+0], sn1 = csr_src[s+1], sn2 = csr_src[s+2], sn3 = csr_src[s+3];
      float nm0 = masked ? nmask[sn0] : 1.f;
      float nm1 = masked ? nmask[sn1] : 1.f;
      float nm2 = masked ? nmask[sn2] : 1.f;
      float nm3 = masked ? nmask[sn3] : 1.f;
      if (nm0 > 0.f){ float4 v = *(const float4*)&X[((size_t)sn0 << 7) + (c4 << 2)];
                      ax += v.x; ay += v.y; az += v.z; aw += v.w; cnt += 1.f; }
      if (nm1 > 0.f){ float4 v = *(const float4*)&X[((size_t)sn1 << 7) + (c4 << 2)];
                      ax += v.x; ay += v.y; az += v.z; aw += v.w; cnt += 1.f; }
      if (nm2 > 0.f){ float4 v = *(const float4*)&X[((size_t)sn2 << 7) + (c4 << 2)];
                      ax += v.x; ay += v.y; az += v.z; aw += v.w; cnt += 1.f; }
      if (nm3 > 0.f){ float4 v = *(const float4*)&X[((size_t)sn3 << 7) + (c4 << 2)];
                      ax += v.x; ay += v.y; az += v.z; aw += v.w; cnt += 1.f; }
    }
    for (; s < r1; s++){
      int sn = csr_src[s];
      float nm = masked ? nmask[sn] : 1.f;
      if (nm > 0.f){
        const float4 v = *(const float4*)&X[((size_t)sn << 7) + (c4 << 2)];
        ax += v.x; ay += v.y; az += v.z; aw += v.w; cnt += 1.f;
      }
    }
  }
  float inv = 1.f / fmaxf(cnt, 1.f);
  float4 o; o.x = ax*inv; o.y = ay*inv; o.z = az*inv; o.w = aw*inv;
  *(float4*)&AGG[((size_t)i << 7) + (c4 << 2)] = o;
}

// ---------------- dual GEMM f32, W-resident, register-parked A pipeline ----------------
// PROVEN core (R5/R7): 71.4 us/dispatch, 64 VGPR, zero scratch, LDS 72.5KB (2 blk/CU).
// REFUTED (R6): full-tile LDS -> 1 blk/CU exposes ds_read latency (78.8us).
// REFUTED (r13-r15): K-chunk W-streaming + dbuf spills at ANY VGPR budget.
// REFUTED (R8): SAGE gather fused into A-prefetch -> 5x FETCH, 231us.
// __launch_bounds__ arg2 on this toolchain = CUDA-style min-BLOCKS-per-CU.
// sc_mode: 0=none, 1=score1 (tanh(dot*inv)), 2=qr dual-dot, 3=GAT heads.
__global__ void __launch_bounds__(512) k_gemm(const float* A1, const float* A2,
    const float* W1, const float* W2, const float* bias,
    float* OUT, int has2, int relu, int hasb,
    const int* ridx, int sc_mode,
    const float* sw1, const float* sw2, const float* sinv,
    float* so1, float* so2){
  __shared__ float ws[128][128];
  __shared__ float as[16][136];
  int t = threadIdx.x;
  int n0 = blockIdx.x * 128;
  int rowg = t >> 5;
  int colg = t & 31;
  int rb = rowg * 8;
  int jb = colg * 4;
  int an = t >> 2;              // A-stage row 0..127
  int ak = (t & 3) << 2;        // A-stage k offset {0,4,8,12}
  int arow = ridx ? ridx[n0 + an] : (n0 + an);
  float acc[8][4];
  for (int r = 0; r < 8; r++)
    for (int j = 0; j < 4; j++) acc[r][j] = 0.f;
  int nmat = has2 ? 2 : 1;
  for (int m = 0; m < nmat; m++){
    const float* A = (m == 0) ? A1 : A2;
    const float* W = (m == 0) ? W1 : W2;
    __syncthreads();   // prior readers of ws/as done (no-op cost at m==0)
    for (int ii = 0; ii < 8; ii++){
      int idx4 = t + 512*ii;
      int kk = idx4 >> 5;
      int jj = (idx4 & 31) << 2;
      *(float4*)&ws[kk][jj] = *(const float4*)&W[kk*128 + jj];
    }
    float4 rA = *(const float4*)&A[((size_t)arow << 7) + ak];   // chunk 0
    for (int c = 0; c < 8; c++){
      if (c > 0) __syncthreads();        // prior compute done reading as
      as[ak+0][an] = rA.x;
      as[ak+1][an] = rA.y;
      as[ak+2][an] = rA.z;
      as[ak+3][an] = rA.w;
      __syncthreads();                   // as (and ws on c==0) visible
      if (c+1 < 8)
        rA = *(const float4*)&A[((size_t)arow << 7) + (c+1)*16 + ak];  // prefetch
      int kb = c*16;
      for (int kk = 0; kk < 16; kk++){
        float4 wv = *(const float4*)&ws[kb+kk][jb];
        float4 aL = *(const float4*)&as[kk][rb];
        float4 aH = *(const float4*)&as[kk][rb+4];
        float a0=aL.x,a1=aL.y,a2=aL.z,a3=aL.w,a4=aH.x,a5=aH.y,a6=aH.z,a7=aH.w;
        acc[0][0]+=a0*wv.x; acc[0][1]+=a0*wv.y; acc[0][2]+=a0*wv.z; acc[0][3]+=a0*wv.w;
        acc[1][0]+=a1*wv.x; acc[1][1]+=a1*wv.y; acc[1][2]+=a1*wv.z; acc[1][3]+=a1*wv.w;
        acc[2][0]+=a2*wv.x; acc[2][1]+=a2*wv.y; acc[2][2]+=a2*wv.z; acc[2][3]+=a2*wv.w;
        acc[3][0]+=a3*wv.x; acc[3][1]+=a3*wv.y; acc[3][2]+=a3*wv.z; acc[3][3]+=a3*wv.w;
        acc[4][0]+=a4*wv.x; acc[4][1]+=a4*wv.y; acc[4][2]+=a4*wv.z; acc[4][3]+=a4*wv.w;
        acc[5][0]+=a5*wv.x; acc[5][1]+=a5*wv.y; acc[5][2]+=a5*wv.z; acc[5][3]+=a5*wv.w;
        acc[6][0]+=a6*wv.x; acc[6][1]+=a6*wv.y; acc[6][2]+=a6*wv.z; acc[6][3]+=a6*wv.w;
        acc[7][0]+=a7*wv.x; acc[7][1]+=a7*wv.y; acc[7][2]+=a7*wv.z; acc[7][3]+=a7*wv.w;
      }
    }
  }
  float bj0=0.f,bj1=0.f,bj2=0.f,bj3=0.f;
  if (hasb){
    bj0 = bias[jb+0]; bj1 = bias[jb+1]; bj2 = bias[jb+2]; bj3 = bias[jb+3];
  }
  int orow[8];
  for (int r = 0; r < 8; r++) orow[r] = ridx ? ridx[n0+rb+r] : (n0+rb+r);
  float w1x=0.f,w1y=0.f,w1z=0.f,w1w=0.f, w2x=0.f,w2y=0.f,w2z=0.f,w2w=0.f;
  if (sc_mode){
    float4 t1 = *(const float4*)&sw1[jb];
    w1x=t1.x; w1y=t1.y; w1z=t1.z; w1w=t1.w;
    if (sc_mode >= 2){
      float4 t2 = *(const float4*)&sw2[jb];
      w2x=t2.x; w2y=t2.y; w2z=t2.z; w2w=t2.w;
    }
  }
  float pd1[8], pd2[8];
  for (int r = 0; r < 8; r++){
    float4 o;
    o.x = acc[r][0]+bj0; o.y = acc[r][1]+bj1; o.z = acc[r][2]+bj2; o.w = acc[r][3]+bj3;
    if (relu){
      o.x = fmaxf(o.x,0.f); o.y = fmaxf(o.y,0.f); o.z = fmaxf(o.z,0.f); o.w = fmaxf(o.w,0.f);
    }
    if (sc_mode){
      pd1[r] = o.x*w1x + o.y*w1y + o.z*w1z + o.w*w1w;
      if (sc_mode >= 2) pd2[r] = o.x*w2x + o.y*w2y + o.z*w2z + o.w*w2w;
    }
    *(float4*)&OUT[((size_t)orow[r] << 7) + jb] = o;
  }
  if (sc_mode == 1){
    float inv = sinv[0];
    for (int r = 0; r < 8; r++){
      float a = pd1[r];
      for (int o = 16; o > 0; o >>= 1) a += __shfl_down(a, o, 32);
      if (colg == 0) so1[orow[r]] = tanhf(a * inv);
    }
  } else if (sc_mode == 2){
    for (int r = 0; r < 8; r++){
      float a = pd1[r];
      float b = pd2[r];
      for (int o = 16; o > 0; o >>= 1){
        a += __shfl_down(a, o, 32);
        b += __shfl_down(b, o, 32);
      }
      if (colg == 0){ so1[orow[r]] = a; so2[orow[r]] = b; }
    }
  } else if (sc_mode == 3){
    // fused k_heads: serial accumulate lanes h*8..h*8+7 in c4 order (bit-exact)
    int base = colg & ~7;
    for (int r = 0; r < 8; r++){
      float s1 = 0.f, s2 = 0.f;
      for (int c4 = 0; c4 < 8; c4++){
        s1 += __shfl(pd1[r], base + c4, 32);
        s2 += __shfl(pd2[r], base + c4, 32);
      }
      if ((colg & 7) == 0){
        int h = colg >> 3;
        so1[orow[r]*4 + h] = s1;
        so2[orow[r]*4 + h] = s2;
      }
    }
  }
}

// gconv with optional compaction: nidx = flat live-node list (length ntot).
// Stale sA entries for dead nodes are masked by nmask before any use in pool.
__global__ void k_gconv(const float* q, const float* r, const float* nmask,
    const int* rp, const int* csr_src, const float* brel, float* s,
    const int* nidx, int ntot){
  int gid = blockIdx.x*blockDim.x + threadIdx.x;
  int i;
  if (nidx){ if (gid >= ntot) return; i = nidx[gid]; }
  else { if (gid >= NBV) return; i = gid; }
  float acc = 0.f;
  if (nmask[i] > 0.f){
    int r0 = rp[i], r1 = rp[i+1];
    int t2 = r0;
    for (; t2 + 4 <= r1; t2 += 4){
      int sn0 = csr_src[t2+0], sn1 = csr_src[t2+1], sn2 = csr_src[t2+2], sn3 = csr_src[t2+3];
      float nm0 = nmask[sn0], nm1 = nmask[sn1], nm2 = nmask[sn2], nm3 = nmask[sn3];
      if (nm0 > 0.f) acc += q[sn0];
      if (nm1 > 0.f) acc += q[sn1];
      if (nm2 > 0.f) acc += q[sn2];
      if (nm3 > 0.f) acc += q[sn3];
    }
    for (; t2 < r1; t2++){
      int sn = csr_src[t2];
      if (nmask[sn] > 0.f) acc += q[sn];
    }
  }
  s[i] = tanhf(acc + brel[0] + r[i]);
}

// ---------------- fused top-k pool + scale + gap (1 launch instead of 3) --------
__global__ void __launch_bounds__(512) k_poolscale(const float* s, float* nmask,
    float* X, float* gap, int K, int* cidx, float invK){
  __shared__ float sc[512];     // scores for rank; reused as live-flags after
  __shared__ float lsel[512];
  __shared__ float prt[8][128];
  int b = blockIdx.x, t = threadIdx.x;
  int i = b*512 + t;
  float nm = nmask[i];
  float sv = s[i];
  float ms = (nm > 0.f) ? sv : NEG_BIG;
  sc[t] = ms;
  __syncthreads();
  int rank = 0;
  for (int j = 0; j < 512; j++){
    float o = sc[j];
    rank += ((o > ms) || (o == ms && j < t)) ? 1 : 0;
  }
  bool selb = rank < K;
  nmask[i] = selb ? 1.f : 0.f;
  if (cidx && selb) cidx[b*K + rank] = i;
  __syncthreads();              // all rank reads of sc done
  sc[t] = selb ? 1.f : 0.f;     // live flag
  lsel[t] = selb ? sv : 0.f;
  __syncthreads();
  int c = t & 127, g = t >> 7;  // 128 cols x 4 groups; group handles q=2g,2g+1
  for (int qq = 0; qq < 2; qq++){
    int q = g*2 + qq;
    float acc = 0.f;
    for (int n = q*64; n < q*64 + 64; n++){
      if (sc[n] > 0.f){
        size_t idx = (((size_t)(b*512 + n)) << 7) + c;
        float v = X[idx] * lsel[n];
        X[idx] = v;
        acc += v;
      }
    }
    prt[q][c] = acc;
  }
  __syncthreads();
  if (t < 128){
    float ss = 0.f;
    for (int q = 0; q < 8; q++) ss += prt[q][t];
    gap[b*128 + t] = ss * invK;
  }
}

// edge-attr masked mean: per-block partials (no atomics)
__global__ void __launch_bounds__(256) k_ea_part(const float* ea, const int* srcA, const int* dstA,
    const float* nmask, float* part){
  float p[8] = {0.f,0.f,0.f,0.f,0.f,0.f,0.f,0.f};
  for (int e = blockIdx.x*256 + threadIdx.x; e < EV; e += 256*256){
    if (nmask[srcA[e]] > 0.f && nmask[dstA[e]] > 0.f){
      for (int d = 0; d < 7; d++) p[d] += ea[e*7 + d];
      p[7] += 1.f;
    }
  }
  __shared__ float red[256];
  for (int comp = 0; comp < 8; comp++){
    red[threadIdx.x] = p[comp]; __syncthreads();
    for (int o = 128; o > 0; o >>= 1){ if (threadIdx.x < o) red[threadIdx.x] += red[threadIdx.x + o]; __syncthreads(); }
    if (threadIdx.x == 0) part[blockIdx.x*8 + comp] = red[0];
    __syncthreads();
  }
}

// merged ea_final + alse
__global__ void k_ea_fin(const float* part, const float* ve, float* alse){
  __shared__ float es[8];
  int h = threadIdx.x;
  if (h < 8){
    float s = 0.f;
    for (int b = 0; b < 256; b++) s += part[b*8 + h];
    es[h] = s;
  }
  __syncthreads();
  if (h == 0){
    float cnt = fmaxf(es[7], 1.f);
    for (int hh = 0; hh < 4; hh++){
      float s = 0.f;
      for (int ed = 0; ed < 7; ed++) s += (es[ed]/cnt) * ve[ed*4 + hh];
      alse[hh] = s;
    }
  }
}

// GAT: 32 threads/node, compacted to live2 nodes, mask-gated gathers + in-order
// online softmax. Epilogue fuses k_qr (p3) bit-exactly (same dot + shfl tree).
__global__ void __launch_bounds__(256) k_gat(const float* xs, const float* alS, const float* alD,
    const float* ALE, const float* nmask, const int* rp, const int* csr_src,
    const int* csr_eid, const float* alse, const float* g_b,
    const float* wrel, const float* wroot, const int* nidx, int kper,
    float* qv, float* rv, float* OUT){
  int g = blockIdx.x & 127;
  int blk = blockIdx.x >> 7;
  int r = blk*8 + (threadIdx.x >> 5);
  int i;
  if (nidx){ if (r >= kper) return; i = nidx[g*kper + r]; }
  else i = g*512 + r;
  int lane = threadIdx.x & 31;
  int h = lane >> 3;
  int ch = h*8 + (lane & 7);   // == lane
  float nmi = nmask[i];
  const float4* xs4 = (const float4*)xs;
  float m = 0.f, den = 0.f;
  float4 acc; acc.x=0.f; acc.y=0.f; acc.z=0.f; acc.w=0.f;
  if (nmi > 0.f){
    float ald_i = alD[i*4 + h];
    m = lrelu(alS[i*4 + h] + ald_i + alse[h]);   // aself
    den = 1.f;
    acc = xs4[(size_t)i*32 + ch];
    int r0 = rp[i], r1 = rp[i+1];
    int s = r0;
    for (; s + 4 <= r1; s += 4){
      int sn0 = csr_src[s+0], sn1 = csr_src[s+1], sn2 = csr_src[s+2], sn3 = csr_src[s+3];
      float nm0 = nmask[sn0], nm1 = nmask[sn1], nm2 = nmask[sn2], nm3 = nmask[sn3];
      if (nm0 > 0.f){
        float a = lrelu(alS[sn0*4 + h] + ald_i + ALE[(size_t)csr_eid[s+0]*4 + h]);
        float4 v = xs4[(size_t)sn0*32 + ch];
        float mn = fmaxf(m, a); float pm = expf(m - mn); float pa = expf(a - mn);
        den = den*pm + pa;
        acc.x = acc.x*pm + pa*v.x; acc.y = acc.y*pm + pa*v.y;
        acc.z = acc.z*pm + pa*v.z; acc.w = acc.w*pm + pa*v.w;
        m = mn;
      }
      if (nm1 > 0.f){
        float a = lrelu(alS[sn1*4 + h] + ald_i + ALE[(size_t)csr_eid[s+1]*4 + h]);
        float4 v = xs4[(size_t)sn1*32 + ch];
        float mn = fmaxf(m, a); float pm = expf(m - mn); float pa = expf(a - mn);
        den = den*pm + pa;
        acc.x = acc.x*pm + pa*v.x; acc.y = acc.y*pm + pa*v.y;
        acc.z = acc.z*pm + pa*v.z; acc.w = acc.w*pm + pa*v.w;
        m = mn;
      }
      if (nm2 > 0.f){
        float a = lrelu(alS[sn2*4 + h] + ald_i + ALE[(size_t)csr_eid[s+2]*4 + h]);
        float4 v = xs4[(size_t)sn2*32 + ch];
        float mn = fmaxf(m, a); float pm = expf(m - mn); float pa = expf(a - mn);
        den = den*pm + pa;
        acc.x = acc.x*pm + pa*v.x; acc.y = acc.y*pm + pa*v.y;
        acc.z = acc.z*pm + pa*v.z; acc.w = acc.w*pm + pa*v.w;
        m = mn;
      }
      if (nm3 > 0.f){
        float a = lrelu(alS[sn3*4 + h] + ald_i + ALE[(size_t)csr_eid[s+3]*4 + h]);
        float4 v = xs4[(size_t)sn3*32 + ch];
        float mn = fmaxf(m, a); float pm = expf(m - mn); float pa = expf(a - mn);
        den = den*pm + pa;
        acc.x = acc.x*pm + pa*v.x; acc.y = acc.y*pm + pa*v.y;
        acc.z = acc.z*pm + pa*v.z; acc.w = acc.w*pm + pa*v.w;
        m = mn;
      }
    }
    for (; s < r1; s++){
      int sn = csr_src[s];
      if (nmask[sn] > 0.f){
        float a = lrelu(alS[sn*4 + h] + ald_i + ALE[(size_t)csr_eid[s]*4 + h]);
        float4 v = xs4[(size_t)sn*32 + ch];
        float mn = fmaxf(m, a); float pm = expf(m - mn); float pa = expf(a - mn);
        den = den*pm + pa;
        acc.x = acc.x*pm + pa*v.x; acc.y = acc.y*pm + pa*v.y;
        acc.z = acc.z*pm + pa*v.z; acc.w = acc.w*pm + pa*v.w;
        m = mn;
      }
    }
  }
  den = fmaxf(den, 1e-16f);
  float rd = 1.f/den;
  int cb = ch << 2;
  float4 o;
  o.x = fmaxf(acc.x*rd + g_b[cb+0], 0.f);
  o.y = fmaxf(acc.y*rd + g_b[cb+1], 0.f);
  o.z = fmaxf(acc.z*rd + g_b[cb+2], 0.f);
  o.w = fmaxf(acc.w*rd + g_b[cb+3], 0.f);
  *(float4*)&OUT[((size_t)i << 7) + cb] = o;
  // fused k_qr (p3): identical per-lane dot + width-32 tree as standalone k_qr
  float4 wa = *(const float4*)&wrel[cb];
  float4 wb = *(const float4*)&wroot[cb];
  float aq = o.x*wa.x + o.y*wa.y + o.z*wa.z + o.w*wa.w;
  float ar = o.x*wb.x + o.y*wb.y + o.z*wb.z + o.w*wb.w;
  for (int off = 16; off > 0; off >>= 1){
    aq += __shfl_down(aq, off, 32);
    ar += __shfl_down(ar, off, 32);
  }
  if (lane == 0){ qv[i] = aq; rv[i] = ar; }
}

// ---------------- final MLP ----------------
__global__ void __launch_bounds__(128) k_mlp(const float* x1g, const float* x2g, const float* x3g,
    const float* l1w, const float* l1b, const float* l2w, const float* l2b,
    const float* l3w, const float* l3b, float* out){
  __shared__ float hh[128];
  __shared__ float h2[128];
  __shared__ float h3[64];
  int b = blockIdx.x, t = threadIdx.x;
  hh[t] = x1g[b*128 + t] + x2g[b*128 + t] + x3g[b*128 + t];
  __syncthreads();
  float a = l1b[t];
  for (int k = 0; k < 128; k++) a += hh[k] * l1w[k*128 + t];
  h2[t] = fmaxf(a, 0.f);
  __syncthreads();
  if (t < 64){
    float a2 = l2b[t];
    for (int k = 0; k < 128; k++) a2 += h2[k] * l2w[k*64 + t];
    h3[t] = fmaxf(a2, 0.f);
  }
  __syncthreads();
  if (t == 0){
    float z = l3b[0];
    for (int k = 0; k < 64; k++) z += h3[k] * l3w[k];
    out[b] = 1.f/(1.f + expf(-z));
  }
}

// ---------------- launch ----------------
extern "C" void kernel_launch(void* const* d_in, const int* in_sizes, int n_in,
                              void* d_out, int out_size, void* d_ws, size_t ws_size,
                              hipStream_t stream){
  const float* x       = (const float*)d_in[0];
  const int*   ei      = (const int*)d_in[1];
  const float* ea      = (const float*)d_in[2];
  const float* c1_wl   = (const float*)d_in[3];
  const float* c1_bl   = (const float*)d_in[4];
  const float* c1_wr   = (const float*)d_in[5];
  const float* p1_w    = (const float*)d_in[6];
  const float* c2_wl   = (const float*)d_in[7];
  const float* c2_bl   = (const float*)d_in[8];
  const float* c2_wr   = (const float*)d_in[9];
  const float* p2_wrel = (const float*)d_in[10];
  const float* p2_brel = (const float*)d_in[11];
  const float* p2_wroot= (const float*)d_in[12];
  const float* g_w     = (const float*)d_in[13];
  const float* g_as    = (const float*)d_in[14];
  const float* g_ad    = (const float*)d_in[15];
  const float* g_we    = (const float*)d_in[16];
  const float* g_ae    = (const float*)d_in[17];
  const float* g_b     = (const float*)d_in[18];
  const float* p3_wrel = (const float*)d_in[19];
  const float* p3_brel = (const float*)d_in[20];
  const float* p3_wroot= (const float*)d_in[21];
  const float* l1_w    = (const float*)d_in[22];
  const float* l1_b    = (const float*)d_in[23];
  const float* l2_w    = (const float*)d_in[24];
  const float* l2_b    = (const float*)d_in[25];
  const float* l3_w    = (const float*)d_in[26];
  const float* l3_b    = (const float*)d_in[27];
  float* out = (float*)d_out;
  (void)in_sizes; (void)n_in; (void)out_size;

  // Workspace layout (f32, ~137 MB)
  char* w = (char*)d_ws;
  size_t off = 0;
  float* AGG  = (float*)(w + off); off += (size_t)NBV*128*4;   // sage out / xs for block 3
  float* F1   = (float*)(w + off); off += (size_t)NBV*128*4;
  float* F2   = (float*)(w + off); off += (size_t)NBV*128*4;
  float* ALE  = (float*)(w + off); off += (size_t)EV*4*4;
  float* sA   = (float*)(w + off); off += (size_t)NBV*4;
  float* qv   = (float*)(w + off); off += (size_t)NBV*4;
  float* rv   = (float*)(w + off); off += (size_t)NBV*4;
  float* nmask= (float*)(w + off); off += (size_t)NBV*4;
  float* alS  = (float*)(w + off); off += (size_t)NBV*4*4;
  float* alD  = (float*)(w + off); off += (size_t)NBV*4*4;
  float* x1g  = (float*)(w + off); off += (size_t)BV*128*4;
  float* x2g  = (float*)(w + off); off += (size_t)BV*128*4;
  float* x3g  = (float*)(w + off); off += (size_t)BV*128*4;
  float* sml  = (float*)(w + off); off += 64*4;      // [0]=invnorm [16..19]=alse [20..47]=ve
  float* eprt = (float*)(w + off); off += 2048*4;
  int* csr_src = (int*)(w + off); off += (size_t)EV*4;
  int* csr_eid = (int*)(w + off); off += (size_t)EV*4;
  int* rp      = (int*)(w + off); off += (size_t)(NBV+64)*4;
  int* dcnt    = (int*)(w + off); off += (size_t)(NBV+64)*4;
  int* fill    = (int*)(w + off); off += (size_t)(NBV+64)*4;
  int* cidx1   = (int*)(w + off); off += (size_t)NBV*4;
  int* cidx2   = (int*)(w + off); off += (size_t)NBV*4;
  int* bsum    = (int*)(w + off); off += 1024;
  size_t needed = off;

  float sentinel = (ws_size >= needed) ? 0.125f : 0.875f;

  const int* srcA = ei;
  const int* dstA = ei + EV;

  // ---- setup (sentinel folded into init1) ----
  k_init1<<<(NBV+256)/256, 256, 0, stream>>>(nmask, dcnt, fill, out, sentinel);
  k_hist<<<EV/256, 256, 0, stream>>>(dstA, dcnt);
  k_scan1<<<256, 256, 0, stream>>>(dcnt, rp, bsum);
  k_scan2<<<1, 256, 0, stream>>>(bsum);
  k_scan3<<<256, 256, 0, stream>>>(rp, dcnt, bsum);
  k_scatter<<<EV/256, 256, 0, stream>>>(srcA, dstA, rp, fill, csr_src, csr_eid);
  k_ve_inv<<<1, 128, 0, stream>>>(g_we, g_ae, p1_w, sml);
  k_ale<<<EV/256, 256, 0, stream>>>(ea, sml+20, ALE);

  // ---- block 1: SAGE -> TopK(410)+scale+gap  (x -> F1; score fused in GEMM) ----
  k_sage_agg<<<(NBV*32)/256, 256, 0, stream>>>(x, nmask, rp, csr_src, AGG, 0,
                                               (const int*)nullptr, 512);
  k_gemm<<<NBV/128, 512, 0, stream>>>(AGG, x, c1_wl, c1_wr, c1_bl, F1, 1, 1, 1,
                                      (const int*)nullptr, 1, p1_w, (const float*)nullptr, sml, sA, (float*)nullptr);
  k_poolscale<<<BV, 512, 0, stream>>>(sA, nmask, F1, x1g, K1V, cidx1, 1.f/(float)K1V);

  // ---- block 2: SAGE(compacted) -> GEMM2(compacted to live1) -> SAGPool(205) ----
  k_sage_agg<<<BV*52, 256, 0, stream>>>(F1, nmask, rp, csr_src, AGG, 1, cidx1, K1V);
  k_gemm<<<NL1/128, 512, 0, stream>>>(AGG, F1, c2_wl, c2_wr, c2_bl, F2, 1, 1, 1,
                                      cidx1, 2, p2_wrel, p2_wroot, (const float*)nullptr, qv, rv);
  k_gconv<<<NL1/256, 256, 0, stream>>>(qv, rv, nmask, rp, csr_src, p2_brel, sA, cidx1, NL1);
  k_poolscale<<<BV, 512, 0, stream>>>(sA, nmask, F2, x2g, K2V, cidx2, 1.f/(float)K2V);

  // ---- block 3: GAT (compacted; heads fused in GEMM3) -> SAGPool(103)+scale+gap ----
  k_gemm<<<NL2/128, 512, 0, stream>>>(F2, F2, g_w, g_w, g_b, AGG, 0, 0, 0,
                                      cidx2, 3, g_as, g_ad,
                                      (const float*)nullptr, alS, alD);
  k_ea_part<<<256, 256, 0, stream>>>(ea, srcA, dstA, nmask, eprt);
  k_ea_fin<<<1, 64, 0, stream>>>(eprt, sml+20, sml+16);
  k_gat<<<BV*26, 256, 0, stream>>>(AGG, alS, alD, ALE, nmask, rp, csr_src, csr_eid,
                                   sml+16, g_b, p3_wrel, p3_wroot, cidx2, K2V, qv, rv, F1);
  k_gconv<<<(NL2+255)/256, 256, 0, stream>>>(qv, rv, nmask, rp, csr_src, p3_brel, sA, cidx2, NL2);
  k_poolscale<<<BV, 512, 0, stream>>>(sA, nmask, F1, x3g, K3V, (int*)nullptr, 1.f/(float)K3V);

  // ---- readout MLP ----
  k_mlp<<<BV, 128, 0, stream>>>(x1g, x2g, x3g, l1_w, l1_b, l2_w, l2_b, l3_w, l3_b, out);
}

// Round 11
// 670.979 us; speedup vs baseline: 1.3003x; 1.0216x over previous
//
#include <hip/hip_runtime.h>
#include <math.h>

#define NBV 65536
#define EV  1048576
#define BV  128
#define K1V 410
#define K2V 205
#define K3V 103
#define NL1 (BV*K1V)     // 52480 live nodes after pool1 (GEMM2 domain)
#define NL2 (BV*K2V)     // 26240 live nodes after pool2 (GEMM3/gat domain)
#define NEG_BIG (-1.0e38f)

__device__ __forceinline__ float lrelu(float x){ return x > 0.f ? x : 0.2f*x; }

// ---------------- init: sentinel + nmask + dcnt + fill (1 launch) ----------------
__global__ void k_init1(float* nmask, int* dcnt, int* fill, float* out, float sval){
  int i = blockIdx.x*blockDim.x + threadIdx.x;
  if (i < 128) out[i] = sval;
  if (i < NBV) nmask[i] = 1.f;
  if (i < NBV+1){ dcnt[i] = 0; fill[i] = 0; }
}

// ---------------- CSR build (int atomics only) ----------------
__global__ void k_hist(const int* dst, int* dcnt){
  int e = blockIdx.x*blockDim.x + threadIdx.x;
  if (e < EV) atomicAdd(&dcnt[dst[e]], 1);
}

__global__ void k_scan1(const int* dcnt, int* rp, int* bsum){
  __shared__ int sc[256];
  int t = threadIdx.x, i = blockIdx.x*256 + t;
  int v = dcnt[i];
  sc[t] = v; __syncthreads();
  for (int o = 1; o < 256; o <<= 1){
    int x = (t >= o) ? sc[t-o] : 0;
    __syncthreads();
    sc[t] += x;
    __syncthreads();
  }
  rp[i] = sc[t];
  if (t == 255) bsum[blockIdx.x] = sc[t];
}

__global__ void k_scan2(int* bsum){
  __shared__ int sc[256];
  int t = threadIdx.x;
  int v = bsum[t];
  sc[t] = v; __syncthreads();
  for (int o = 1; o < 256; o <<= 1){
    int x = (t >= o) ? sc[t-o] : 0;
    __syncthreads();
    sc[t] += x;
    __syncthreads();
  }
  bsum[t] = sc[t] - v;
}

__global__ void k_scan3(int* rp, const int* dcnt, const int* bsum){
  int t = threadIdx.x, i = blockIdx.x*256 + t;
  rp[i] = rp[i] - dcnt[i] + bsum[blockIdx.x];
  if (i == 0) rp[NBV] = EV;
}

// ---------------- small precomputes (merged: ve + invnorm, 1 launch) ----------------
__global__ void k_ve_inv(const float* g_we, const float* g_ae, const float* p1w, float* sml){
  __shared__ float sc[128];
  int t = threadIdx.x;
  if (t < 28){
    int ed = t >> 2, h = t & 3;
    float a = 0.f;
    for (int c = 0; c < 32; c++) a += g_we[ed*128 + h*32 + c] * g_ae[h*32 + c];
    sml[20 + t] = a;
  }
  float v = p1w[t];
  sc[t] = v*v; __syncthreads();
  for (int o = 64; o > 0; o >>= 1){ if (t < o) sc[t] += sc[t+o]; __syncthreads(); }
  if (t == 0) sml[0] = 1.f / sqrtf(sc[0]);
}

// ---------------- CSR scatter + ALE precompute (merged; independent work) ---------
__global__ void k_scatter_ale(const int* src, const int* dst, const int* rp, int* fill,
                              int* csr_src, int* csr_eid,
                              const float* ea, const float* ve, float* ALE){
  int e = blockIdx.x*blockDim.x + threadIdx.x;
  if (e < EV){
    int d = dst[e];
    int pos = atomicAdd(&fill[d], 1);
    int slot = rp[d] + pos;
    csr_src[slot] = src[e];
    csr_eid[slot] = e;
    float a0=0.f,a1=0.f,a2=0.f,a3=0.f;
    for (int ed = 0; ed < 7; ed++){
      float x2 = ea[e*7 + ed];
      a0 += x2*ve[ed*4+0]; a1 += x2*ve[ed*4+1]; a2 += x2*ve[ed*4+2]; a3 += x2*ve[ed*4+3];
    }
    float4 o; o.x=a0; o.y=a1; o.z=a2; o.w=a3;
    *(float4*)&ALE[(size_t)e*4] = o;
  }
}

// ---------------- SAGE mean aggregation (XCD-swizzled; optional compaction) ----------------
// REFUTED (r18/R8): fusing this gather into the GEMM A-prefetch slot costs 5x
// FETCH and serializes the accumulate chain -> 231us. Keep standalone:
// 32 lanes/node read each 512B neighbor row once, fully coalesced.
__global__ void __launch_bounds__(256) k_sage_agg(const float* X, const float* nmask,
    const int* rp, const int* csr_src, float* AGG, int masked,
    const int* nidx, int kper){
  int g = blockIdx.x & 127;
  int blk = blockIdx.x >> 7;
  int r = blk*8 + (threadIdx.x >> 5);
  int i;
  if (nidx){ if (r >= kper) return; i = nidx[g*kper + r]; }
  else i = g*512 + r;
  int c4 = threadIdx.x & 31;
  float ax=0.f,ay=0.f,az=0.f,aw=0.f,cnt=0.f;
  if (!masked || nmask[i] > 0.f){
    int r0 = rp[i], r1 = rp[i+1];
    int s = r0;
    for (; s + 4 <= r1; s += 4){
      int sn0 = csr_src[s+0], sn1 = csr_src[s+1], sn2 = csr_src[s+2], sn3 = csr_src[s+3];
      float nm0 = masked ? nmask[sn0] : 1.f;
      float nm1 = masked ? nmask[sn1] : 1.f;
      float nm2 = masked ? nmask[sn2] : 1.f;
      float nm3 = masked ? nmask[sn3] : 1.f;
      if (nm0 > 0.f){ float4 v = *(const float4*)&X[((size_t)sn0 << 7) + (c4 << 2)];
                      ax += v.x; ay += v.y; az += v.z; aw += v.w; cnt += 1.f; }
      if (nm1 > 0.f){ float4 v = *(const float4*)&X[((size_t)sn1 << 7) + (c4 << 2)];
                      ax += v.x; ay += v.y; az += v.z; aw += v.w; cnt += 1.f; }
      if (nm2 > 0.f){ float4 v = *(const float4*)&X[((size_t)sn2 << 7) + (c4 << 2)];
                      ax += v.x; ay += v.y; az += v.z; aw += v.w; cnt += 1.f; }
      if (nm3 > 0.f){ float4 v = *(const float4*)&X[((size_t)sn3 << 7) + (c4 << 2)];
                      ax += v.x; ay += v.y; az += v.z; aw += v.w; cnt += 1.f; }
    }
    for (; s < r1; s++){
      int sn = csr_src[s];
      float nm = masked ? nmask[sn] : 1.f;
      if (nm > 0.f){
        const float4 v = *(const float4*)&X[((size_t)sn << 7) + (c4 << 2)];
        ax += v.x; ay += v.y; az += v.z; aw += v.w; cnt += 1.f;
      }
    }
  }
  float inv = 1.f / fmaxf(cnt, 1.f);
  float4 o; o.x = ax*inv; o.y = ay*inv; o.z = az*inv; o.w = aw*inv;
  *(float4*)&AGG[((size_t)i << 7) + (c4 << 2)] = o;
}

// ---------------- dual GEMM f32, W-resident, register-parked A pipeline ----------------
// PROVEN core (R5/R7/R10): ~70 us/dispatch, 64 VGPR, zero scratch, LDS 72.5KB (2 blk/CU).
// REFUTED (R6): full-tile LDS -> 1 blk/CU exposes ds_read latency (78.8us).
// REFUTED (r13-r15): K-chunk W-streaming + dbuf spills at ANY VGPR budget.
// REFUTED (R8): SAGE gather fused into A-prefetch -> 5x FETCH, 231us.
// __launch_bounds__ arg2 on this toolchain = CUDA-style min-BLOCKS-per-CU.
// sc_mode: 0=none, 1=score1 (tanh(dot*inv)), 2=qr dual-dot, 3=GAT heads.
__global__ void __launch_bounds__(512) k_gemm(const float* A1, const float* A2,
    const float* W1, const float* W2, const float* bias,
    float* OUT, int has2, int relu, int hasb,
    const int* ridx, int sc_mode,
    const float* sw1, const float* sw2, const float* sinv,
    float* so1, float* so2){
  __shared__ float ws[128][128];
  __shared__ float as[16][136];
  int t = threadIdx.x;
  int n0 = blockIdx.x * 128;
  int rowg = t >> 5;
  int colg = t & 31;
  int rb = rowg * 8;
  int jb = colg * 4;
  int an = t >> 2;              // A-stage row 0..127
  int ak = (t & 3) << 2;        // A-stage k offset {0,4,8,12}
  int arow = ridx ? ridx[n0 + an] : (n0 + an);
  float acc[8][4];
  for (int r = 0; r < 8; r++)
    for (int j = 0; j < 4; j++) acc[r][j] = 0.f;
  int nmat = has2 ? 2 : 1;
  for (int m = 0; m < nmat; m++){
    const float* A = (m == 0) ? A1 : A2;
    const float* W = (m == 0) ? W1 : W2;
    __syncthreads();   // prior readers of ws/as done (no-op cost at m==0)
    for (int ii = 0; ii < 8; ii++){
      int idx4 = t + 512*ii;
      int kk = idx4 >> 5;
      int jj = (idx4 & 31) << 2;
      *(float4*)&ws[kk][jj] = *(const float4*)&W[kk*128 + jj];
    }
    float4 rA = *(const float4*)&A[((size_t)arow << 7) + ak];   // chunk 0
    for (int c = 0; c < 8; c++){
      if (c > 0) __syncthreads();        // prior compute done reading as
      as[ak+0][an] = rA.x;
      as[ak+1][an] = rA.y;
      as[ak+2][an] = rA.z;
      as[ak+3][an] = rA.w;
      __syncthreads();                   // as (and ws on c==0) visible
      if (c+1 < 8)
        rA = *(const float4*)&A[((size_t)arow << 7) + (c+1)*16 + ak];  // prefetch
      int kb = c*16;
      for (int kk = 0; kk < 16; kk++){
        float4 wv = *(const float4*)&ws[kb+kk][jb];
        float4 aL = *(const float4*)&as[kk][rb];
        float4 aH = *(const float4*)&as[kk][rb+4];
        float a0=aL.x,a1=aL.y,a2=aL.z,a3=aL.w,a4=aH.x,a5=aH.y,a6=aH.z,a7=aH.w;
        acc[0][0]+=a0*wv.x; acc[0][1]+=a0*wv.y; acc[0][2]+=a0*wv.z; acc[0][3]+=a0*wv.w;
        acc[1][0]+=a1*wv.x; acc[1][1]+=a1*wv.y; acc[1][2]+=a1*wv.z; acc[1][3]+=a1*wv.w;
        acc[2][0]+=a2*wv.x; acc[2][1]+=a2*wv.y; acc[2][2]+=a2*wv.z; acc[2][3]+=a2*wv.w;
        acc[3][0]+=a3*wv.x; acc[3][1]+=a3*wv.y; acc[3][2]+=a3*wv.z; acc[3][3]+=a3*wv.w;
        acc[4][0]+=a4*wv.x; acc[4][1]+=a4*wv.y; acc[4][2]+=a4*wv.z; acc[4][3]+=a4*wv.w;
        acc[5][0]+=a5*wv.x; acc[5][1]+=a5*wv.y; acc[5][2]+=a5*wv.z; acc[5][3]+=a5*wv.w;
        acc[6][0]+=a6*wv.x; acc[6][1]+=a6*wv.y; acc[6][2]+=a6*wv.z; acc[6][3]+=a6*wv.w;
        acc[7][0]+=a7*wv.x; acc[7][1]+=a7*wv.y; acc[7][2]+=a7*wv.z; acc[7][3]+=a7*wv.w;
      }
    }
  }
  float bj0=0.f,bj1=0.f,bj2=0.f,bj3=0.f;
  if (hasb){
    bj0 = bias[jb+0]; bj1 = bias[jb+1]; bj2 = bias[jb+2]; bj3 = bias[jb+3];
  }
  int orow[8];
  for (int r = 0; r < 8; r++) orow[r] = ridx ? ridx[n0+rb+r] : (n0+rb+r);
  float w1x=0.f,w1y=0.f,w1z=0.f,w1w=0.f, w2x=0.f,w2y=0.f,w2z=0.f,w2w=0.f;
  if (sc_mode){
    float4 t1 = *(const float4*)&sw1[jb];
    w1x=t1.x; w1y=t1.y; w1z=t1.z; w1w=t1.w;
    if (sc_mode >= 2){
      float4 t2 = *(const float4*)&sw2[jb];
      w2x=t2.x; w2y=t2.y; w2z=t2.z; w2w=t2.w;
    }
  }
  float pd1[8], pd2[8];
  for (int r = 0; r < 8; r++){
    float4 o;
    o.x = acc[r][0]+bj0; o.y = acc[r][1]+bj1; o.z = acc[r][2]+bj2; o.w = acc[r][3]+bj3;
    if (relu){
      o.x = fmaxf(o.x,0.f); o.y = fmaxf(o.y,0.f); o.z = fmaxf(o.z,0.f); o.w = fmaxf(o.w,0.f);
    }
    if (sc_mode){
      pd1[r] = o.x*w1x + o.y*w1y + o.z*w1z + o.w*w1w;
      if (sc_mode >= 2) pd2[r] = o.x*w2x + o.y*w2y + o.z*w2z + o.w*w2w;
    }
    *(float4*)&OUT[((size_t)orow[r] << 7) + jb] = o;
  }
  if (sc_mode == 1){
    float inv = sinv[0];
    for (int r = 0; r < 8; r++){
      float a = pd1[r];
      for (int o = 16; o > 0; o >>= 1) a += __shfl_down(a, o, 32);
      if (colg == 0) so1[orow[r]] = tanhf(a * inv);
    }
  } else if (sc_mode == 2){
    for (int r = 0; r < 8; r++){
      float a = pd1[r];
      float b = pd2[r];
      for (int o = 16; o > 0; o >>= 1){
        a += __shfl_down(a, o, 32);
        b += __shfl_down(b, o, 32);
      }
      if (colg == 0){ so1[orow[r]] = a; so2[orow[r]] = b; }
    }
  } else if (sc_mode == 3){
    // fused k_heads: serial accumulate lanes h*8..h*8+7 in c4 order (bit-exact)
    int base = colg & ~7;
    for (int r = 0; r < 8; r++){
      float s1 = 0.f, s2 = 0.f;
      for (int c4 = 0; c4 < 8; c4++){
        s1 += __shfl(pd1[r], base + c4, 32);
        s2 += __shfl(pd2[r], base + c4, 32);
      }
      if ((colg & 7) == 0){
        int h = colg >> 3;
        so1[orow[r]*4 + h] = s1;
        so2[orow[r]*4 + h] = s2;
      }
    }
  }
}

// ---------------- fused (gconv) + top-k pool + scale + gap -----------------------
// mode 0: score = sIn[i] (block 1; sIn from GEMM1 epilogue).
// mode 1: score = tanh(sum_{s in CSR order, live src} qv[src] + brel + rv[i])
//   — gconv fused: edges are INTRA-GRAPH by construction, so qv/nmask for the
//   graph's 512 nodes are preloaded to LDS and gathered locally. Ascending-s
//   add order == old k_gconv's 4-unroll order -> bit-exact.
// rank loop identical to proven k_pool (stable tie-break == jax.lax.top_k).
__global__ void __launch_bounds__(512) k_poolscale(const float* sIn,
    const float* qv, const float* rv, const float* brel,
    const int* rp, const int* csr_src,
    float* nmask, float* X, float* gap, int K, int* cidx, float invK, int mode){
  __shared__ float qls[512];
  __shared__ float nml[512];
  __shared__ float sc[512];     // scores for rank; reused as live-flags after
  __shared__ float lsel[512];
  __shared__ float prt[8][128];
  int b = blockIdx.x, t = threadIdx.x;
  int i = b*512 + t;
  float nm = nmask[i];
  float sv = 0.f;
  if (mode){
    qls[t] = qv[i];
    nml[t] = nm;
    __syncthreads();
    if (nm > 0.f){
      float acc = 0.f;
      int r0 = rp[i], r1 = rp[i+1];
      int base = b*512;
      for (int s = r0; s < r1; s++){
        int ln = csr_src[s] - base;      // intra-graph guaranteed
        if (nml[ln] > 0.f) acc += qls[ln];
      }
      sv = tanhf(acc + brel[0] + rv[i]);
    }
  } else {
    sv = sIn[i];
  }
  float ms = (nm > 0.f) ? sv : NEG_BIG;
  sc[t] = ms;
  __syncthreads();
  int rank = 0;
  for (int j = 0; j < 512; j++){
    float o = sc[j];
    rank += ((o > ms) || (o == ms && j < t)) ? 1 : 0;
  }
  bool selb = rank < K;
  nmask[i] = selb ? 1.f : 0.f;
  if (cidx && selb) cidx[b*K + rank] = i;
  __syncthreads();              // all rank reads of sc done
  sc[t] = selb ? 1.f : 0.f;     // live flag
  lsel[t] = selb ? sv : 0.f;
  __syncthreads();
  int c = t & 127, g = t >> 7;  // 128 cols x 4 groups; group handles q=2g,2g+1
  for (int qq = 0; qq < 2; qq++){
    int q = g*2 + qq;
    float acc = 0.f;
    for (int n = q*64; n < q*64 + 64; n++){
      if (sc[n] > 0.f){
        size_t idx = (((size_t)(b*512 + n)) << 7) + c;
        float v = X[idx] * lsel[n];
        X[idx] = v;
        acc += v;
      }
    }
    prt[q][c] = acc;
  }
  __syncthreads();
  if (t < 128){
    float ss = 0.f;
    for (int q = 0; q < 8; q++) ss += prt[q][t];
    gap[b*128 + t] = ss * invK;
  }
}

// edge-attr masked mean: per-block partials (no atomics)
__global__ void __launch_bounds__(256) k_ea_part(const float* ea, const int* srcA, const int* dstA,
    const float* nmask, float* part){
  float p[8] = {0.f,0.f,0.f,0.f,0.f,0.f,0.f,0.f};
  for (int e = blockIdx.x*256 + threadIdx.x; e < EV; e += 256*256){
    if (nmask[srcA[e]] > 0.f && nmask[dstA[e]] > 0.f){
      for (int d = 0; d < 7; d++) p[d] += ea[e*7 + d];
      p[7] += 1.f;
    }
  }
  __shared__ float red[256];
  for (int comp = 0; comp < 8; comp++){
    red[threadIdx.x] = p[comp]; __syncthreads();
    for (int o = 128; o > 0; o >>= 1){ if (threadIdx.x < o) red[threadIdx.x] += red[threadIdx.x + o]; __syncthreads(); }
    if (threadIdx.x == 0) part[blockIdx.x*8 + comp] = red[0];
    __syncthreads();
  }
}

// merged ea_final + alse
__global__ void k_ea_fin(const float* part, const float* ve, float* alse){
  __shared__ float es[8];
  int h = threadIdx.x;
  if (h < 8){
    float s = 0.f;
    for (int b = 0; b < 256; b++) s += part[b*8 + h];
    es[h] = s;
  }
  __syncthreads();
  if (h == 0){
    float cnt = fmaxf(es[7], 1.f);
    for (int hh = 0; hh < 4; hh++){
      float s = 0.f;
      for (int ed = 0; ed < 7; ed++) s += (es[ed]/cnt) * ve[ed*4 + hh];
      alse[hh] = s;
    }
  }
}

// GAT: 32 threads/node, compacted to live2 nodes, mask-gated gathers + in-order
// online softmax. Epilogue fuses k_qr (p3) bit-exactly (same dot + shfl tree).
__global__ void __launch_bounds__(256) k_gat(const float* xs, const float* alS, const float* alD,
    const float* ALE, const float* nmask, const int* rp, const int* csr_src,
    const int* csr_eid, const float* alse, const float* g_b,
    const float* wrel, const float* wroot, const int* nidx, int kper,
    float* qv, float* rv, float* OUT){
  int g = blockIdx.x & 127;
  int blk = blockIdx.x >> 7;
  int r = blk*8 + (threadIdx.x >> 5);
  int i;
  if (nidx){ if (r >= kper) return; i = nidx[g*kper + r]; }
  else i = g*512 + r;
  int lane = threadIdx.x & 31;
  int h = lane >> 3;
  int ch = h*8 + (lane & 7);   // == lane
  float nmi = nmask[i];
  const float4* xs4 = (const float4*)xs;
  float m = 0.f, den = 0.f;
  float4 acc; acc.x=0.f; acc.y=0.f; acc.z=0.f; acc.w=0.f;
  if (nmi > 0.f){
    float ald_i = alD[i*4 + h];
    m = lrelu(alS[i*4 + h] + ald_i + alse[h]);   // aself
    den = 1.f;
    acc = xs4[(size_t)i*32 + ch];
    int r0 = rp[i], r1 = rp[i+1];
    int s = r0;
    for (; s + 4 <= r1; s += 4){
      int sn0 = csr_src[s+0], sn1 = csr_src[s+1], sn2 = csr_src[s+2], sn3 = csr_src[s+3];
      float nm0 = nmask[sn0], nm1 = nmask[sn1], nm2 = nmask[sn2], nm3 = nmask[sn3];
      if (nm0 > 0.f){
        float a = lrelu(alS[sn0*4 + h] + ald_i + ALE[(size_t)csr_eid[s+0]*4 + h]);
        float4 v = xs4[(size_t)sn0*32 + ch];
        float mn = fmaxf(m, a); float pm = expf(m - mn); float pa = expf(a - mn);
        den = den*pm + pa;
        acc.x = acc.x*pm + pa*v.x; acc.y = acc.y*pm + pa*v.y;
        acc.z = acc.z*pm + pa*v.z; acc.w = acc.w*pm + pa*v.w;
        m = mn;
      }
      if (nm1 > 0.f){
        float a = lrelu(alS[sn1*4 + h] + ald_i + ALE[(size_t)csr_eid[s+1]*4 + h]);
        float4 v = xs4[(size_t)sn1*32 + ch];
        float mn = fmaxf(m, a); float pm = expf(m - mn); float pa = expf(a - mn);
        den = den*pm + pa;
        acc.x = acc.x*pm + pa*v.x; acc.y = acc.y*pm + pa*v.y;
        acc.z = acc.z*pm + pa*v.z; acc.w = acc.w*pm + pa*v.w;
        m = mn;
      }
      if (nm2 > 0.f){
        float a = lrelu(alS[sn2*4 + h] + ald_i + ALE[(size_t)csr_eid[s+2]*4 + h]);
        float4 v = xs4[(size_t)sn2*32 + ch];
        float mn = fmaxf(m, a); float pm = expf(m - mn); float pa = expf(a - mn);
        den = den*pm + pa;
        acc.x = acc.x*pm + pa*v.x; acc.y = acc.y*pm + pa*v.y;
        acc.z = acc.z*pm + pa*v.z; acc.w = acc.w*pm + pa*v.w;
        m = mn;
      }
      if (nm3 > 0.f){
        float a = lrelu(alS[sn3*4 + h] + ald_i + ALE[(size_t)csr_eid[s+3]*4 + h]);
        float4 v = xs4[(size_t)sn3*32 + ch];
        float mn = fmaxf(m, a); float pm = expf(m - mn); float pa = expf(a - mn);
        den = den*pm + pa;
        acc.x = acc.x*pm + pa*v.x; acc.y = acc.y*pm + pa*v.y;
        acc.z = acc.z*pm + pa*v.z; acc.w = acc.w*pm + pa*v.w;
        m = mn;
      }
    }
    for (; s < r1; s++){
      int sn = csr_src[s];
      if (nmask[sn] > 0.f){
        float a = lrelu(alS[sn*4 + h] + ald_i + ALE[(size_t)csr_eid[s]*4 + h]);
        float4 v = xs4[(size_t)sn*32 + ch];
        float mn = fmaxf(m, a); float pm = expf(m - mn); float pa = expf(a - mn);
        den = den*pm + pa;
        acc.x = acc.x*pm + pa*v.x; acc.y = acc.y*pm + pa*v.y;
        acc.z = acc.z*pm + pa*v.z; acc.w = acc.w*pm + pa*v.w;
        m = mn;
      }
    }
  }
  den = fmaxf(den, 1e-16f);
  float rd = 1.f/den;
  int cb = ch << 2;
  float4 o;
  o.x = fmaxf(acc.x*rd + g_b[cb+0], 0.f);
  o.y = fmaxf(acc.y*rd + g_b[cb+1], 0.f);
  o.z = fmaxf(acc.z*rd + g_b[cb+2], 0.f);
  o.w = fmaxf(acc.w*rd + g_b[cb+3], 0.f);
  *(float4*)&OUT[((size_t)i << 7) + cb] = o;
  // fused k_qr (p3): identical per-lane dot + width-32 tree as standalone k_qr
  float4 wa = *(const float4*)&wrel[cb];
  float4 wb = *(const float4*)&wroot[cb];
  float aq = o.x*wa.x + o.y*wa.y + o.z*wa.z + o.w*wa.w;
  float ar = o.x*wb.x + o.y*wb.y + o.z*wb.z + o.w*wb.w;
  for (int off = 16; off > 0; off >>= 1){
    aq += __shfl_down(aq, off, 32);
    ar += __shfl_down(ar, off, 32);
  }
  if (lane == 0){ qv[i] = aq; rv[i] = ar; }
}

// ---------------- final MLP ----------------
__global__ void __launch_bounds__(128) k_mlp(const float* x1g, const float* x2g, const float* x3g,
    const float* l1w, const float* l1b, const float* l2w, const float* l2b,
    const float* l3w, const float* l3b, float* out){
  __shared__ float hh[128];
  __shared__ float h2[128];
  __shared__ float h3[64];
  int b = blockIdx.x, t = threadIdx.x;
  hh[t] = x1g[b*128 + t] + x2g[b*128 + t] + x3g[b*128 + t];
  __syncthreads();
  float a = l1b[t];
  for (int k = 0; k < 128; k++) a += hh[k] * l1w[k*128 + t];
  h2[t] = fmaxf(a, 0.f);
  __syncthreads();
  if (t < 64){
    float a2 = l2b[t];
    for (int k = 0; k < 128; k++) a2 += h2[k] * l2w[k*64 + t];
    h3[t] = fmaxf(a2, 0.f);
  }
  __syncthreads();
  if (t == 0){
    float z = l3b[0];
    for (int k = 0; k < 64; k++) z += h3[k] * l3w[k];
    out[b] = 1.f/(1.f + expf(-z));
  }
}

// ---------------- launch ----------------
extern "C" void kernel_launch(void* const* d_in, const int* in_sizes, int n_in,
                              void* d_out, int out_size, void* d_ws, size_t ws_size,
                              hipStream_t stream){
  const float* x       = (const float*)d_in[0];
  const int*   ei      = (const int*)d_in[1];
  const float* ea      = (const float*)d_in[2];
  const float* c1_wl   = (const float*)d_in[3];
  const float* c1_bl   = (const float*)d_in[4];
  const float* c1_wr   = (const float*)d_in[5];
  const float* p1_w    = (const float*)d_in[6];
  const float* c2_wl   = (const float*)d_in[7];
  const float* c2_bl   = (const float*)d_in[8];
  const float* c2_wr   = (const float*)d_in[9];
  const float* p2_wrel = (const float*)d_in[10];
  const float* p2_brel = (const float*)d_in[11];
  const float* p2_wroot= (const float*)d_in[12];
  const float* g_w     = (const float*)d_in[13];
  const float* g_as    = (const float*)d_in[14];
  const float* g_ad    = (const float*)d_in[15];
  const float* g_we    = (const float*)d_in[16];
  const float* g_ae    = (const float*)d_in[17];
  const float* g_b     = (const float*)d_in[18];
  const float* p3_wrel = (const float*)d_in[19];
  const float* p3_brel = (const float*)d_in[20];
  const float* p3_wroot= (const float*)d_in[21];
  const float* l1_w    = (const float*)d_in[22];
  const float* l1_b    = (const float*)d_in[23];
  const float* l2_w    = (const float*)d_in[24];
  const float* l2_b    = (const float*)d_in[25];
  const float* l3_w    = (const float*)d_in[26];
  const float* l3_b    = (const float*)d_in[27];
  float* out = (float*)d_out;
  (void)in_sizes; (void)n_in; (void)out_size;

  // Workspace layout (f32, ~137 MB)
  char* w = (char*)d_ws;
  size_t off = 0;
  float* AGG  = (float*)(w + off); off += (size_t)NBV*128*4;   // sage out / xs for block 3
  float* F1   = (float*)(w + off); off += (size_t)NBV*128*4;
  float* F2   = (float*)(w + off); off += (size_t)NBV*128*4;
  float* ALE  = (float*)(w + off); off += (size_t)EV*4*4;
  float* sA   = (float*)(w + off); off += (size_t)NBV*4;
  float* qv   = (float*)(w + off); off += (size_t)NBV*4;
  float* rv   = (float*)(w + off); off += (size_t)NBV*4;
  float* nmask= (float*)(w + off); off += (size_t)NBV*4;
  float* alS  = (float*)(w + off); off += (size_t)NBV*4*4;
  float* alD  = (float*)(w + off); off += (size_t)NBV*4*4;
  float* x1g  = (float*)(w + off); off += (size_t)BV*128*4;
  float* x2g  = (float*)(w + off); off += (size_t)BV*128*4;
  float* x3g  = (float*)(w + off); off += (size_t)BV*128*4;
  float* sml  = (float*)(w + off); off += 64*4;      // [0]=invnorm [16..19]=alse [20..47]=ve
  float* eprt = (float*)(w + off); off += 2048*4;
  int* csr_src = (int*)(w + off); off += (size_t)EV*4;
  int* csr_eid = (int*)(w + off); off += (size_t)EV*4;
  int* rp      = (int*)(w + off); off += (size_t)(NBV+64)*4;
  int* dcnt    = (int*)(w + off); off += (size_t)(NBV+64)*4;
  int* fill    = (int*)(w + off); off += (size_t)(NBV+64)*4;
  int* cidx1   = (int*)(w + off); off += (size_t)NBV*4;
  int* cidx2   = (int*)(w + off); off += (size_t)NBV*4;
  int* bsum    = (int*)(w + off); off += 1024;
  size_t needed = off;

  float sentinel = (ws_size >= needed) ? 0.125f : 0.875f;

  const int* srcA = ei;
  const int* dstA = ei + EV;

  // ---- setup (sentinel folded into init1; ale folded into scatter) ----
  k_init1<<<(NBV+256)/256, 256, 0, stream>>>(nmask, dcnt, fill, out, sentinel);
  k_hist<<<EV/256, 256, 0, stream>>>(dstA, dcnt);
  k_scan1<<<256, 256, 0, stream>>>(dcnt, rp, bsum);
  k_scan2<<<1, 256, 0, stream>>>(bsum);
  k_scan3<<<256, 256, 0, stream>>>(rp, dcnt, bsum);
  k_ve_inv<<<1, 128, 0, stream>>>(g_we, g_ae, p1_w, sml);
  k_scatter_ale<<<EV/256, 256, 0, stream>>>(srcA, dstA, rp, fill, csr_src, csr_eid,
                                            ea, sml+20, ALE);

  // ---- block 1: SAGE -> GEMM(score fused) -> TopK(410)+scale+gap ----
  k_sage_agg<<<(NBV*32)/256, 256, 0, stream>>>(x, nmask, rp, csr_src, AGG, 0,
                                               (const int*)nullptr, 512);
  k_gemm<<<NBV/128, 512, 0, stream>>>(AGG, x, c1_wl, c1_wr, c1_bl, F1, 1, 1, 1,
                                      (const int*)nullptr, 1, p1_w, (const float*)nullptr, sml, sA, (float*)nullptr);
  k_poolscale<<<BV, 512, 0, stream>>>(sA, (const float*)nullptr, (const float*)nullptr,
                                      (const float*)nullptr, (const int*)nullptr, (const int*)nullptr,
                                      nmask, F1, x1g, K1V, cidx1, 1.f/(float)K1V, 0);

  // ---- block 2: SAGE(compacted) -> GEMM2(compacted, qr fused) -> gconv+pool fused ----
  k_sage_agg<<<BV*52, 256, 0, stream>>>(F1, nmask, rp, csr_src, AGG, 1, cidx1, K1V);
  k_gemm<<<NL1/128, 512, 0, stream>>>(AGG, F1, c2_wl, c2_wr, c2_bl, F2, 1, 1, 1,
                                      cidx1, 2, p2_wrel, p2_wroot, (const float*)nullptr, qv, rv);
  k_poolscale<<<BV, 512, 0, stream>>>((const float*)nullptr, qv, rv, p2_brel, rp, csr_src,
                                      nmask, F2, x2g, K2V, cidx2, 1.f/(float)K2V, 1);

  // ---- block 3: GEMM3(heads fused) -> ea -> GAT(qr fused) -> gconv+pool fused ----
  k_gemm<<<NL2/128, 512, 0, stream>>>(F2, F2, g_w, g_w, g_b, AGG, 0, 0, 0,
                                      cidx2, 3, g_as, g_ad,
                                      (const float*)nullptr, alS, alD);
  k_ea_part<<<256, 256, 0, stream>>>(ea, srcA, dstA, nmask, eprt);
  k_ea_fin<<<1, 64, 0, stream>>>(eprt, sml+20, sml+16);
  k_gat<<<BV*26, 256, 0, stream>>>(AGG, alS, alD, ALE, nmask, rp, csr_src, csr_eid,
                                   sml+16, g_b, p3_wrel, p3_wroot, cidx2, K2V, qv, rv, F1);
  k_poolscale<<<BV, 512, 0, stream>>>((const float*)nullptr, qv, rv, p3_brel, rp, csr_src,
                                      nmask, F1, x3g, K3V, (int*)nullptr, 1.f/(float)K3V, 1);

  // ---- readout MLP ----
  k_mlp<<<BV, 128, 0, stream>>>(x1g, x2g, x3g, l1_w, l1_b, l2_w, l2_b, l3_w, l3_b, out);
}